// Round 1
// baseline (6288.802 us; speedup 1.0000x reference)
//
#include <hip/hip_runtime.h>
#include <hip/hip_bf16.h>
#include <cmath>

#define HID 512
#define FOURH 2048
#define BATCH 256
#define TSTEPS 784
#define NCLS 10

typedef __bf16 bf16x8 __attribute__((ext_vector_type(8)));
typedef __bf16 bf16x4 __attribute__((ext_vector_type(4)));
typedef float f32x4 __attribute__((ext_vector_type(4)));

// fp32 -> bf16 weight conversion (runs every call; deterministic)
__global__ void convert_w(const float* __restrict__ w, __bf16* __restrict__ wb, int n) {
    int i = (blockIdx.x * blockDim.x + threadIdx.x) * 4;
    if (i < n) {
        float4 v = *reinterpret_cast<const float4*>(w + i);
        bf16x4 o;
        o[0] = (__bf16)v.x; o[1] = (__bf16)v.y; o[2] = (__bf16)v.z; o[3] = (__bf16)v.w;
        *reinterpret_cast<bf16x4*>(wb + i) = o;
    }
}

__global__ void zero_ws(uint4* p, int n16) {
    int i = blockIdx.x * blockDim.x + threadIdx.x;
    if (i < n16) p[i] = make_uint4(0u, 0u, 0u, 0u);
}

// One LSTM timestep: gates = hin @ Wb^T (+x*w_in + bias), cell update, write hout.
// Grid: 256 blocks = 16 batch-tiles(16) x 16 h-slices(32). 256 threads = 4 waves.
// Wave w computes gate type s=w for its 32-wide h-slice: compact cols cn = w*32 + nt*16 + (lane&15).
__global__ __launch_bounds__(256)
void lstm_step(const __bf16* __restrict__ Wb,   // [2048][512] bf16
               const __bf16* __restrict__ hin,  // [256][512] bf16
               __bf16* __restrict__ hout,
               float* __restrict__ c,           // [256][512] fp32, in-place
               const float* __restrict__ x,     // inputs [256][784]
               const float* __restrict__ w_in,  // [2048]
               const float* __restrict__ b_ih,
               const float* __restrict__ b_hh,
               float* __restrict__ hf32,
               int t, int last)
{
    __shared__ float gl[16][129];   // gates tile fp32, padded

    const int tid  = threadIdx.x;
    const int lane = tid & 63;
    const int w    = tid >> 6;          // wave id = gate type s
    const int bm   = blockIdx.x & 15;   // batch tile
    const int jb   = blockIdx.x >> 4;   // h-slice
    const int b0   = bm * 16;
    const int j0   = jb * 32;

    const int rlo = lane & 15;
    const int khi = (lane >> 4) * 8;

    // A fragment source: h rows b0..b0+15
    const __bf16* aptr = hin + (b0 + rlo) * HID + khi;
    // B fragment sources: W rows  s*512 + j0 + nt*16 + rlo
    const __bf16* bptr0 = Wb + (w * HID + j0 +  0 + rlo) * HID + khi;
    const __bf16* bptr1 = Wb + (w * HID + j0 + 16 + rlo) * HID + khi;

    f32x4 acc0 = {0.f, 0.f, 0.f, 0.f};
    f32x4 acc1 = {0.f, 0.f, 0.f, 0.f};

    #pragma unroll
    for (int ks = 0; ks < 16; ++ks) {
        bf16x8 a  = *reinterpret_cast<const bf16x8*>(aptr  + ks * 32);
        bf16x8 bA = *reinterpret_cast<const bf16x8*>(bptr0 + ks * 32);
        bf16x8 bB = *reinterpret_cast<const bf16x8*>(bptr1 + ks * 32);
        acc0 = __builtin_amdgcn_mfma_f32_16x16x32_bf16(a, bA, acc0, 0, 0, 0);
        acc1 = __builtin_amdgcn_mfma_f32_16x16x32_bf16(a, bB, acc1, 0, 0, 0);
    }

    // D layout: col = lane&15 (the W row / gate col), row = (lane>>4)*4 + reg (batch)
    #pragma unroll
    for (int r = 0; r < 4; ++r) {
        int bl = (lane >> 4) * 4 + r;
        gl[bl][w * 32 +  0 + rlo] = acc0[r];
        gl[bl][w * 32 + 16 + rlo] = acc1[r];
    }
    __syncthreads();

    // Cell update: 16 batch x 32 h outputs = 512, 2 per thread
    const int bl = tid >> 4;            // 0..15
    const int gb = b0 + bl;
    const float xv = x[gb * TSTEPS + t];

    #pragma unroll
    for (int ii = 0; ii < 2; ++ii) {
        int jj = (tid & 15) * 2 + ii;
        int gj = j0 + jj;
        float g4[4];
        #pragma unroll
        for (int s = 0; s < 4; ++s) {
            int rs = s * HID + gj;
            g4[s] = gl[bl][s * 32 + jj] + xv * w_in[rs] + b_ih[rs] + b_hh[rs];
        }
        float ig = 1.f / (1.f + expf(-g4[0]));
        float fg = 1.f / (1.f + expf(-g4[1]));
        float gg = tanhf(g4[2]);
        float og = 1.f / (1.f + expf(-g4[3]));
        float cn = fg * c[gb * HID + gj] + ig * gg;
        c[gb * HID + gj] = cn;
        float hn = og * tanhf(cn);
        hout[gb * HID + gj] = (__bf16)hn;
        if (last) hf32[gb * HID + gj] = hn;
    }
}

// out[b][j] = h_T[b] . W_lin[j] + b_lin[j]
__global__ void head(const float* __restrict__ hf, const float* __restrict__ Wl,
                     const float* __restrict__ bl_, float* __restrict__ out)
{
    __shared__ float hr[HID];
    int b = blockIdx.x;
    for (int k = threadIdx.x; k < HID; k += blockDim.x) hr[k] = hf[b * HID + k];
    __syncthreads();
    int j = threadIdx.x;
    if (j < NCLS) {
        float acc = bl_[j];
        for (int k = 0; k < HID; ++k) acc += hr[k] * Wl[j * HID + k];
        out[b * NCLS + j] = acc;
    }
}

extern "C" void kernel_launch(void* const* d_in, const int* in_sizes, int n_in,
                              void* d_out, int out_size, void* d_ws, size_t ws_size,
                              hipStream_t stream) {
    const float* inputs = (const float*)d_in[0];
    const float* W_ih   = (const float*)d_in[1];
    const float* W_hh   = (const float*)d_in[2];
    const float* b_ih   = (const float*)d_in[3];
    const float* b_hh   = (const float*)d_in[4];
    const float* W_lin  = (const float*)d_in[5];
    const float* b_lin  = (const float*)d_in[6];

    // ws layout: Wb 2MB | h0 256KB | h1 256KB | c 512KB | hf32 512KB
    const size_t NEEDED = (2u << 20) + (256u << 10) * 2 + (512u << 10) * 2;
    if (ws_size < NEEDED) return;  // fail validation cleanly rather than corrupt

    char* ws = (char*)d_ws;
    __bf16* Wb = (__bf16*)ws;
    __bf16* h0 = (__bf16*)(ws + (2u << 20));
    __bf16* h1 = (__bf16*)(ws + (2u << 20) + (256u << 10));
    float*  c  = (float*)(ws + (2u << 20) + (512u << 10));
    float*  hf = (float*)(ws + (2u << 20) + (1024u << 10));

    convert_w<<<FOURH * HID / 4 / 256, 256, 0, stream>>>(W_hh, Wb, FOURH * HID);
    // zero h0, h1, c (contiguous 1 MB)
    zero_ws<<<(1u << 20) / 16 / 256, 256, 0, stream>>>((uint4*)h0, (1u << 20) / 16);

    for (int t = 0; t < TSTEPS; ++t) {
        const __bf16* hin = (t & 1) ? h1 : h0;
        __bf16* hout      = (t & 1) ? h0 : h1;
        lstm_step<<<256, 256, 0, stream>>>(Wb, hin, hout, c, inputs, W_ih, b_ih, b_hh,
                                           hf, t, (t == TSTEPS - 1) ? 1 : 0);
    }
    head<<<BATCH, 64, 0, stream>>>(hf, W_lin, b_lin, (float*)d_out);
}